// Round 1
// baseline (623.306 us; speedup 1.0000x reference)
//
#include <hip/hip_runtime.h>
#include <cmath>

// Problem constants (match reference)
constexpr int B  = 4096;
constexpr int K  = 512;
constexpr int T  = 30;
constexpr int NT = 256;            // threads per block
constexpr int PT = K / NT;         // 2 candidates per thread
constexpr int NW = NT / 64;        // 4 waves per block
constexpr int MAX_GUESSES  = 6;
constexpr float MISS_THRESH = 2.0f;

// One block per batch row b.
__global__ __launch_bounds__(NT) void score_classify_kernel(
    const float* __restrict__ outp,    // [B*K]  candidate scores
    const float* __restrict__ cand,    // [B,K,T,2]
    const float* __restrict__ gt,      // [B,T,2]
    const float* __restrict__ scales,  // [B]
    float* __restrict__ result)        // [1]
{
    const int b    = blockIdx.x;
    const int tid  = threadIdx.x;
    const int wave = tid >> 6;
    const int lane = tid & 63;

    __shared__ float s_fde[K];
    __shared__ float s_red[3 * NW];
    __shared__ int   s_redi[NW];
    __shared__ float s_bcast[2];
    __shared__ int   s_bi;

    // broadcast loads (L2-served)
    const float2 g  = *(const float2*)(gt + ((size_t)b * T + (T - 1)) * 2);
    const float  sc = scales[b];

    float o[PT], f[PT];
#pragma unroll
    for (int j = 0; j < PT; ++j) {
        const int k = tid + j * NT;
        // only the LAST timestep is consumed by the reference
        const float2 c = *(const float2*)(cand + (((size_t)(b * K + k)) * T + (T - 1)) * 2);
        const float dx = c.x - g.x;
        const float dy = c.y - g.y;
        f[j] = sc * sqrtf(dx * dx + dy * dy);
        s_fde[k] = f[j];
        o[j] = outp[(size_t)b * K + k];
    }

    // ---- phase 1: m_o = max(out), m_s = max(-fde) ----
    float m_o = fmaxf(o[0], o[1]);
    float m_s = fmaxf(-f[0], -f[1]);
    for (int off = 32; off >= 1; off >>= 1) {
        m_o = fmaxf(m_o, __shfl_down(m_o, off));
        m_s = fmaxf(m_s, __shfl_down(m_s, off));
    }
    if (lane == 0) { s_red[wave] = m_o; s_red[NW + wave] = m_s; }
    __syncthreads();
    if (tid == 0) {
        float a = s_red[0], c2 = s_red[NW];
        for (int w = 1; w < NW; ++w) {
            a  = fmaxf(a,  s_red[w]);
            c2 = fmaxf(c2, s_red[NW + w]);
        }
        s_bcast[0] = a; s_bcast[1] = c2;
    }
    __syncthreads();
    m_o = s_bcast[0];
    m_s = s_bcast[1];

    // ---- phase 2: Z_out, Z_s, S = sum e^{-fde-m_s} * out ----
    float zo = 0.f, zs = 0.f, ss = 0.f;
#pragma unroll
    for (int j = 0; j < PT; ++j) {
        zo += expf(o[j] - m_o);
        const float e = expf(-f[j] - m_s);   // TEMP == 1
        zs += e;
        ss += e * o[j];
    }
    for (int off = 32; off >= 1; off >>= 1) {
        zo += __shfl_down(zo, off);
        zs += __shfl_down(zs, off);
        ss += __shfl_down(ss, off);
    }
    __syncthreads();   // s_red reuse
    if (lane == 0) { s_red[wave] = zo; s_red[NW + wave] = zs; s_red[2 * NW + wave] = ss; }
    __syncthreads();
    float cls = 0.f;
    if (tid == 0) {
        float tzo = 0.f, tzs = 0.f, tss = 0.f;
        for (int w = 0; w < NW; ++w) {
            tzo += s_red[w];
            tzs += s_red[NW + w];
            tss += s_red[2 * NW + w];
        }
        // cls = logsumexp(out) - sum(tgt * out)   (sum(tgt) == 1)
        cls = m_o + logf(tzo) - tss / tzs;
    }

    // ---- phase 3: top-6 of out (value desc, lowest-index tiebreak), min fde ----
    bool used[PT];
#pragma unroll
    for (int j = 0; j < PT; ++j) used[j] = false;
    float minfde = 1e30f;

    for (int gidx = 0; gidx < MAX_GUESSES; ++gidx) {
        float bv = -1e30f;
        int   bi = 0x7fffffff;
#pragma unroll
        for (int j = 0; j < PT; ++j) {
            const int k = tid + j * NT;
            if (!used[j] && (o[j] > bv || (o[j] == bv && k < bi))) { bv = o[j]; bi = k; }
        }
        for (int off = 32; off >= 1; off >>= 1) {
            const float v2 = __shfl_down(bv, off);
            const int   i2 = __shfl_down(bi, off);
            if (v2 > bv || (v2 == bv && i2 < bi)) { bv = v2; bi = i2; }
        }
        __syncthreads();   // s_red/s_redi reuse across iterations
        if (lane == 0) { s_red[wave] = bv; s_redi[wave] = bi; }
        __syncthreads();
        if (tid == 0) {
            float v = s_red[0]; int i = s_redi[0];
            for (int w = 1; w < NW; ++w) {
                if (s_red[w] > v || (s_red[w] == v && s_redi[w] < i)) { v = s_red[w]; i = s_redi[w]; }
            }
            s_bi = i;
        }
        __syncthreads();
        const int widx = s_bi;
        if ((widx & (NT - 1)) == tid) used[widx >> 8] = true;  // owner masks it out
        minfde = fminf(minfde, s_fde[widx]);
    }

    if (tid == 0) {
        const float miss = fmaxf(minfde - MISS_THRESH, 0.0f);
        atomicAdd(result, (cls + miss) * (1.0f / (float)B));
    }
}

extern "C" void kernel_launch(void* const* d_in, const int* in_sizes, int n_in,
                              void* d_out, int out_size, void* d_ws, size_t ws_size,
                              hipStream_t stream) {
    const float* outp   = (const float*)d_in[0];  // (B*K, 1) f32
    const float* cand   = (const float*)d_in[1];  // (B, K, T, 2) f32
    const float* gt     = (const float*)d_in[2];  // (B, T, 2) f32
    const float* scales = (const float*)d_in[3];  // (B,) f32
    float* result = (float*)d_out;                // scalar

    // d_out is poisoned with 0xAA before every timed launch — zero it first.
    hipMemsetAsync(result, 0, sizeof(float), stream);
    score_classify_kernel<<<B, NT, 0, stream>>>(outp, cand, gt, scales, result);
}

// Round 2
// 617.249 us; speedup vs baseline: 1.0098x; 1.0098x over previous
//
#include <hip/hip_runtime.h>
#include <cmath>

// Problem constants (match reference)
constexpr int B  = 4096;
constexpr int K  = 512;
constexpr int T  = 30;
constexpr int NT = 256;            // threads per block
constexpr int PT = K / NT;         // 2 candidates per thread
constexpr int NW = NT / 64;        // 4 waves per block
constexpr int MAX_GUESSES  = 6;
constexpr float MISS_THRESH = 2.0f;

// Kernel A: one block per batch row b. Writes per-row loss to part[b].
__global__ __launch_bounds__(NT) void score_classify_kernel(
    const float* __restrict__ outp,    // [B*K]  candidate scores
    const float* __restrict__ cand,    // [B,K,T,2]
    const float* __restrict__ gt,      // [B,T,2]
    const float* __restrict__ scales,  // [B]
    float* __restrict__ part)          // [B] per-row (cls+miss)
{
    const int b    = blockIdx.x;
    const int tid  = threadIdx.x;
    const int wave = tid >> 6;
    const int lane = tid & 63;

    __shared__ float s_fde[K];
    __shared__ float s_red[3 * NW];
    __shared__ int   s_redi[NW];
    __shared__ float s_bcast[2];
    __shared__ int   s_bi;

    // broadcast loads (L2-served)
    const float2 g  = *(const float2*)(gt + ((size_t)b * T + (T - 1)) * 2);
    const float  sc = scales[b];

    float o[PT], f[PT];
#pragma unroll
    for (int j = 0; j < PT; ++j) {
        const int k = tid + j * NT;
        // only the LAST timestep is consumed by the reference
        const float2 c = *(const float2*)(cand + (((size_t)(b * K + k)) * T + (T - 1)) * 2);
        const float dx = c.x - g.x;
        const float dy = c.y - g.y;
        f[j] = sc * sqrtf(dx * dx + dy * dy);
        s_fde[k] = f[j];
        o[j] = outp[(size_t)b * K + k];
    }

    // ---- phase 1: m_o = max(out), m_s = max(-fde) ----
    float m_o = fmaxf(o[0], o[1]);
    float m_s = fmaxf(-f[0], -f[1]);
    for (int off = 32; off >= 1; off >>= 1) {
        m_o = fmaxf(m_o, __shfl_down(m_o, off));
        m_s = fmaxf(m_s, __shfl_down(m_s, off));
    }
    if (lane == 0) { s_red[wave] = m_o; s_red[NW + wave] = m_s; }
    __syncthreads();
    if (tid == 0) {
        float a = s_red[0], c2 = s_red[NW];
        for (int w = 1; w < NW; ++w) {
            a  = fmaxf(a,  s_red[w]);
            c2 = fmaxf(c2, s_red[NW + w]);
        }
        s_bcast[0] = a; s_bcast[1] = c2;
    }
    __syncthreads();
    m_o = s_bcast[0];
    m_s = s_bcast[1];

    // ---- phase 2: Z_out, Z_s, S = sum e^{-fde-m_s} * out ----
    float zo = 0.f, zs = 0.f, ss = 0.f;
#pragma unroll
    for (int j = 0; j < PT; ++j) {
        zo += expf(o[j] - m_o);
        const float e = expf(-f[j] - m_s);   // TEMP == 1
        zs += e;
        ss += e * o[j];
    }
    for (int off = 32; off >= 1; off >>= 1) {
        zo += __shfl_down(zo, off);
        zs += __shfl_down(zs, off);
        ss += __shfl_down(ss, off);
    }
    __syncthreads();   // s_red reuse
    if (lane == 0) { s_red[wave] = zo; s_red[NW + wave] = zs; s_red[2 * NW + wave] = ss; }
    __syncthreads();
    float cls = 0.f;
    if (tid == 0) {
        float tzo = 0.f, tzs = 0.f, tss = 0.f;
        for (int w = 0; w < NW; ++w) {
            tzo += s_red[w];
            tzs += s_red[NW + w];
            tss += s_red[2 * NW + w];
        }
        // cls = logsumexp(out) - sum(tgt * out)   (sum(tgt) == 1)
        cls = m_o + logf(tzo) - tss / tzs;
    }

    // ---- phase 3: top-6 of out (value desc, lowest-index tiebreak), min fde ----
    bool used[PT];
#pragma unroll
    for (int j = 0; j < PT; ++j) used[j] = false;
    float minfde = 1e30f;

    for (int gidx = 0; gidx < MAX_GUESSES; ++gidx) {
        float bv = -1e30f;
        int   bi = 0x7fffffff;
#pragma unroll
        for (int j = 0; j < PT; ++j) {
            const int k = tid + j * NT;
            if (!used[j] && (o[j] > bv || (o[j] == bv && k < bi))) { bv = o[j]; bi = k; }
        }
        for (int off = 32; off >= 1; off >>= 1) {
            const float v2 = __shfl_down(bv, off);
            const int   i2 = __shfl_down(bi, off);
            if (v2 > bv || (v2 == bv && i2 < bi)) { bv = v2; bi = i2; }
        }
        __syncthreads();   // s_red/s_redi reuse across iterations
        if (lane == 0) { s_red[wave] = bv; s_redi[wave] = bi; }
        __syncthreads();
        if (tid == 0) {
            float v = s_red[0]; int i = s_redi[0];
            for (int w = 1; w < NW; ++w) {
                if (s_red[w] > v || (s_red[w] == v && s_redi[w] < i)) { v = s_red[w]; i = s_redi[w]; }
            }
            s_bi = i;
        }
        __syncthreads();
        const int widx = s_bi;
        if ((widx & (NT - 1)) == tid) used[widx >> 8] = true;  // owner masks it out
        minfde = fminf(minfde, s_fde[widx]);
    }

    if (tid == 0) {
        const float miss = fmaxf(minfde - MISS_THRESH, 0.0f);
        part[b] = cls + miss;      // no atomics: one coalesced store per block
    }
}

// Kernel B: single block reduces the 4096 per-row losses to the mean.
__global__ __launch_bounds__(NT) void reduce_mean_kernel(
    const float* __restrict__ part,   // [B]
    float* __restrict__ result)       // [1]
{
    const int tid  = threadIdx.x;
    const int wave = tid >> 6;
    const int lane = tid & 63;
    __shared__ float s_red[NW];

    float acc = 0.f;
#pragma unroll
    for (int i = tid; i < B; i += NT) acc += part[i];
    for (int off = 32; off >= 1; off >>= 1) acc += __shfl_down(acc, off);
    if (lane == 0) s_red[wave] = acc;
    __syncthreads();
    if (tid == 0) {
        float t = 0.f;
        for (int w = 0; w < NW; ++w) t += s_red[w];
        result[0] = t * (1.0f / (float)B);
    }
}

extern "C" void kernel_launch(void* const* d_in, const int* in_sizes, int n_in,
                              void* d_out, int out_size, void* d_ws, size_t ws_size,
                              hipStream_t stream) {
    const float* outp   = (const float*)d_in[0];  // (B*K, 1) f32
    const float* cand   = (const float*)d_in[1];  // (B, K, T, 2) f32
    const float* gt     = (const float*)d_in[2];  // (B, T, 2) f32
    const float* scales = (const float*)d_in[3];  // (B,) f32
    float* result = (float*)d_out;                // scalar
    float* part   = (float*)d_ws;                 // [B] partials (written before read)

    score_classify_kernel<<<B, NT, 0, stream>>>(outp, cand, gt, scales, part);
    reduce_mean_kernel<<<1, NT, 0, stream>>>(part, result);
}

// Round 3
// 612.121 us; speedup vs baseline: 1.0183x; 1.0084x over previous
//
#include <hip/hip_runtime.h>
#include <cmath>

// Problem constants (match reference)
constexpr int B  = 4096;
constexpr int K  = 512;
constexpr int T  = 30;
constexpr int NT = 64;             // ONE wave per block: no __syncthreads, no LDS
constexpr int PT = K / NT;         // 8 candidates per lane
constexpr int MAX_GUESSES  = 6;
constexpr float MISS_THRESH = 2.0f;

// Kernel A: one wave per batch row b. Writes per-row loss to part[b].
__global__ __launch_bounds__(NT) void score_classify_kernel(
    const float* __restrict__ outp,    // [B*K]  candidate scores
    const float* __restrict__ cand,    // [B,K,T,2]
    const float* __restrict__ gt,      // [B,T,2]
    const float* __restrict__ scales,  // [B]
    float* __restrict__ part)          // [B] per-row (cls+miss)
{
    const int b    = blockIdx.x;
    const int lane = threadIdx.x;      // 0..63

    // broadcast loads (L2-served)
    const float2 g  = *(const float2*)(gt + ((size_t)b * T + (T - 1)) * 2);
    const float  sc = scales[b];

    // ---- gather: issue all 8 scattered loads first for MLP ----
    float2 c[PT];
    float  o[PT];
#pragma unroll
    for (int j = 0; j < PT; ++j) {
        const int k = lane + j * NT;
        // only the LAST timestep is consumed by the reference
        c[j] = *(const float2*)(cand + (((size_t)(b * K + k)) * T + (T - 1)) * 2);
        o[j] = outp[(size_t)b * K + k];
    }

    float f[PT];
#pragma unroll
    for (int j = 0; j < PT; ++j) {
        const float dx = c[j].x - g.x;
        const float dy = c[j].y - g.y;
        f[j] = sc * sqrtf(dx * dx + dy * dy);
    }

    // ---- phase 1: m_o = max(out), m_s = max(-fde), butterfly (all lanes get result) ----
    float m_o = o[0], m_s = -f[0];
#pragma unroll
    for (int j = 1; j < PT; ++j) {
        m_o = fmaxf(m_o, o[j]);
        m_s = fmaxf(m_s, -f[j]);
    }
#pragma unroll
    for (int off = 32; off >= 1; off >>= 1) {
        m_o = fmaxf(m_o, __shfl_xor(m_o, off));
        m_s = fmaxf(m_s, __shfl_xor(m_s, off));
    }

    // ---- phase 2: Z_out, Z_s, S = sum e^{-fde-m_s} * out ----
    float zo = 0.f, zs = 0.f, ss = 0.f;
#pragma unroll
    for (int j = 0; j < PT; ++j) {
        zo += expf(o[j] - m_o);
        const float e = expf(-f[j] - m_s);   // TEMP == 1
        zs += e;
        ss += e * o[j];
    }
#pragma unroll
    for (int off = 32; off >= 1; off >>= 1) {
        zo += __shfl_xor(zo, off);
        zs += __shfl_xor(zs, off);
        ss += __shfl_xor(ss, off);
    }
    // cls = logsumexp(out) - sum(tgt * out)   (sum(tgt) == 1); uniform across lanes
    const float cls = m_o + logf(zo) - ss / zs;

    // ---- phase 3: top-6 of out (value desc, lowest-index tiebreak), min fde ----
    unsigned used = 0;                 // per-lane bitmask over my PT slots
    float minfde = 1e30f;

    for (int gidx = 0; gidx < MAX_GUESSES; ++gidx) {
        float bv = -1e30f;
        int   bi = 0x7fffffff;
#pragma unroll
        for (int j = 0; j < PT; ++j) {
            const int k = lane + j * NT;
            const bool ok = !(used & (1u << j));
            if (ok && (o[j] > bv || (o[j] == bv && k < bi))) { bv = o[j]; bi = k; }
        }
        // butterfly argmax: all lanes converge to the same (bv, bi)
#pragma unroll
        for (int off = 32; off >= 1; off >>= 1) {
            const float v2 = __shfl_xor(bv, off);
            const int   i2 = __shfl_xor(bi, off);
            if (v2 > bv || (v2 == bv && i2 < bi)) { bv = v2; bi = i2; }
        }
        const int owner = bi & (NT - 1);   // lane holding the winner
        const int jw    = bi >> 6;         // its register slot (uniform across lanes)
        if (lane == owner) used |= (1u << jw);
        // fetch f[jw] from the owner lane: predicated register select, then shuffle
        float fv = f[0];
#pragma unroll
        for (int j = 1; j < PT; ++j) if (j == jw) fv = f[j];
        const float wfde = __shfl(fv, owner);
        minfde = fminf(minfde, wfde);
    }

    if (lane == 0) {
        const float miss = fmaxf(minfde - MISS_THRESH, 0.0f);
        part[b] = cls + miss;      // one coalesced store per row
    }
}

// Kernel B: single block reduces the 4096 per-row losses to the mean.
__global__ __launch_bounds__(256) void reduce_mean_kernel(
    const float* __restrict__ part,   // [B]
    float* __restrict__ result)       // [1]
{
    const int tid  = threadIdx.x;
    const int wave = tid >> 6;
    const int lane = tid & 63;
    __shared__ float s_red[4];

    float acc = 0.f;
#pragma unroll
    for (int i = tid; i < B; i += 256) acc += part[i];
#pragma unroll
    for (int off = 32; off >= 1; off >>= 1) acc += __shfl_down(acc, off);
    if (lane == 0) s_red[wave] = acc;
    __syncthreads();
    if (tid == 0) {
        float t = 0.f;
        for (int w = 0; w < 4; ++w) t += s_red[w];
        result[0] = t * (1.0f / (float)B);
    }
}

extern "C" void kernel_launch(void* const* d_in, const int* in_sizes, int n_in,
                              void* d_out, int out_size, void* d_ws, size_t ws_size,
                              hipStream_t stream) {
    const float* outp   = (const float*)d_in[0];  // (B*K, 1) f32
    const float* cand   = (const float*)d_in[1];  // (B, K, T, 2) f32
    const float* gt     = (const float*)d_in[2];  // (B, T, 2) f32
    const float* scales = (const float*)d_in[3];  // (B,) f32
    float* result = (float*)d_out;                // scalar
    float* part   = (float*)d_ws;                 // [B] partials (written before read)

    score_classify_kernel<<<B, NT, 0, stream>>>(outp, cand, gt, scales, part);
    reduce_mean_kernel<<<1, 256, 0, stream>>>(part, result);
}